// Round 11
// baseline (1521.007 us; speedup 1.0000x reference)
//
#include <hip/hip_runtime.h>
#include <hip/hip_bf16.h>
#include <stdint.h>

// TreeLSTM on MI355X (gfx950) — fully fused subtree kernel, v8.
// v8: 4 level-3 roots per block (grid 8192), all GEMM steps G=1, LDS cut to
// ~27.5KB so 4 blocks/CU (32 waves = HW max) fit even under the ~8KiB LDS
// allocation granularity inferred from r4-r10 occupancy data. Register
// profile strictly smaller than the proven VGPR=64 body. Keeps: in-place
// c-arena ([p][34], level-l slot s at s<<l), XOR-swizzled B-tiles, exp/rcp
// activations, per-level logits emit, idempotent weight packing in d_ws.

#define THREADS 512

typedef __attribute__((ext_vector_type(8))) short short8;
typedef __attribute__((ext_vector_type(4))) float f32x4;

__device__ __forceinline__ unsigned short f2bf(float x) {
    unsigned u = __float_as_uint(x);
    u += 0x7fffu + ((u >> 16) & 1u);   // round-to-nearest-even
    return (unsigned short)(u >> 16);
}
__device__ __forceinline__ float bf2f(unsigned short b) {
    return __uint_as_float(((unsigned)b) << 16);
}
__device__ __forceinline__ float rcp_fast(float x) { return __builtin_amdgcn_rcpf(x); }
__device__ __forceinline__ float sigm(float x) { return rcp_fast(1.f + __expf(-x)); }
__device__ __forceinline__ float tanh_fast(float x) {
    float e = __expf(2.f * x);
    return (e - 1.f) * rcp_fast(e + 1.f);
}

// ---------------------------------------------------------------------------
// Pack W_iou (384x256) -> Wl ; [U_iou (384x256); U_f (256x256)] -> Wc (640x256)
__global__ __launch_bounds__(256)
void prep_kernel(const float* __restrict__ W_iou,
                 const float* __restrict__ U_iou,
                 const float* __restrict__ U_f,
                 unsigned short* __restrict__ Wl,
                 unsigned short* __restrict__ Wc)
{
    const int i = blockIdx.x * 256 + threadIdx.x;   // grid covers 98304
    if (i < 98304) {
        Wl[i] = f2bf(W_iou[i]);
        Wc[i] = f2bf(U_iou[i]);
    }
    if (i < 65536) {
        Wc[98304 + i] = f2bf(U_f[i]);
    }
}

// ---------------------------------------------------------------------------
// One level's GEMM + LSTM epilogue (G=1: 16 B-tile rows).
// B-tile rows (512B, XOR-16B-chunk swizzled): row j = [h_prev[2j]|h_prev[2j+1]]
// (leaves: row i = emb[tok[i]]). Swapped MFMA: D[n][node]; wave w owns the
// p-slice [16w,16w+16); col groups n = p + j*128 keep i,o,u,f0,f1 in one lane.
// c-arena: [p=128][34] ushort; level-l slot s at index s<<l. CW = 1<<level.
// Children of output node ml sit at CW*ml and CW*ml + CW/2; own c is written
// at CW*ml (aliases first child; same thread reads both first -> safe; writes
// are always even indices, cross-thread reads of odd indices never collide).
template<int NCOL, int CW, bool WC>
__device__ __forceinline__ void level_step(
    const unsigned short* __restrict__ Wg,     // [NCOL*128][256] bf16, global
    const unsigned char* Blds,                 // B-tile base in LDS (16 rows)
    unsigned char* h_out,                      // LDS, B-tile format for next level
    unsigned short* cAr,                       // LDS c-arena, stride 34 per p
    const float* __restrict__ b_iou, const float* __restrict__ b_f,
    int w, int lrow, int lk, int slotBase, int mrows)
{
    const int q0 = w * 16;
    const unsigned char* wbase = reinterpret_cast<const unsigned char*>(Wg)
                               + (q0 + lrow) * 512 + lk * 16;

    f32x4 acc[NCOL];
    #pragma unroll
    for (int j = 0; j < NCOL; ++j)
        acc[j] = (f32x4){0.f, 0.f, 0.f, 0.f};

    #pragma unroll
    for (int ks = 0; ks < 8; ++ks) {
        short8 aW[NCOL];
        #pragma unroll
        for (int j = 0; j < NCOL; ++j)
            aW[j] = *reinterpret_cast<const short8*>(
                wbase + j * 65536 + ks * 64);
        const int chunk = (ks * 4 + lk) ^ (lrow & 7);
        short8 bN = *reinterpret_cast<const short8*>(
            Blds + lrow * 512 + (chunk << 4));
        #pragma unroll
        for (int j = 0; j < NCOL; ++j)
            acc[j] = __builtin_amdgcn_mfma_f32_16x16x32_bf16(
                aW[j], bN, acc[j], 0, 0, 0);
    }

    const int mlB = lrow;                       // B-tile row index (G=1)
    if (mlB < mrows) {
        const int ml = slotBase + mlB;          // output slot this level
        #pragma unroll
        for (int r = 0; r < 4; ++r) {
            const int p = q0 + lk * 4 + r;
            float iv = acc[0][r] + b_iou[p];
            float ov = acc[1][r] + b_iou[128 + p];
            float uv = acc[2][r] + b_iou[256 + p];
            float csum = 0.f;
            if (NCOL == 5) {
                float f0 = acc[3][r] + b_f[p];
                float f1 = acc[4][r] + b_f[128 + p];
                const int cb = p * 34 + CW * mlB;
                csum = sigm(f0) * bf2f(cAr[cb])
                     + sigm(f1) * bf2f(cAr[cb + CW / 2]);
            }
            float cv = sigm(iv) * tanh_fast(uv) + csum;
            float hv = sigm(ov) * tanh_fast(cv);
            if (WC) cAr[p * 34 + CW * ml] = f2bf(cv);
            const int jr = ml >> 1;
            const int q = (ml & 1) * 16 + (p >> 3);
            *reinterpret_cast<unsigned short*>(
                h_out + jr * 512 + ((q ^ (jr & 7)) << 4) + (p & 7) * 2)
                = f2bf(hv);
        }
    }
}

// logits for M local nodes from swizzled LDS h; 4 lanes per node.
__device__ __forceinline__ void logits_emit(
    const unsigned char* h_lds, int M, const int* idsLds, int idBase,
    int segOff, const float* __restrict__ W_lin, const float* __restrict__ b_lin,
    float* __restrict__ out, int t)
{
    const int s = t >> 2, sub = t & 3;
    if (s >= M) return;
    float hv[32];
    const int j = s >> 1;
    #pragma unroll
    for (int qq = 0; qq < 4; ++qq) {
        const int q = (s & 1) * 16 + sub * 4 + qq;
        short8 v = *reinterpret_cast<const short8*>(
            h_lds + j * 512 + ((q ^ (j & 7)) << 4));
        #pragma unroll
        for (int e = 0; e < 8; ++e) hv[qq * 8 + e] = bf2f((unsigned short)v[e]);
    }
    const int gid = idsLds ? idsLds[s] : (idBase + s);
    float dots[5];
    #pragma unroll
    for (int cl = 0; cl < 5; ++cl) {
        const float* wr = W_lin + cl * 128 + sub * 32;
        float d = 0.f;
        #pragma unroll
        for (int k = 0; k < 32; ++k) d += hv[k] * wr[k];
        d += __shfl_xor(d, 1);
        d += __shfl_xor(d, 2);
        dots[cl] = d;
    }
    if (sub == 0) {
        float* op = out + (size_t)(segOff + gid) * 5;
        #pragma unroll
        for (int cl = 0; cl < 5; ++cl)
            op[cl] = dots[cl] + b_lin[cl];
    }
}

// ---------------------------------------------------------------------------
__global__ __launch_bounds__(THREADS, 4)   // VGPR cap 128; body compiles ~<=64
void tree_kernel(const int*  __restrict__ leaf_x,
                 const int2* __restrict__ cpairs,   // l1:[0,131072) l2:+131072 l3:+196608
                 const float* __restrict__ emb,
                 const unsigned short* __restrict__ Wl,
                 const unsigned short* __restrict__ Wc,
                 const float* __restrict__ b_iou,
                 const float* __restrict__ b_f,
                 const float* __restrict__ W_lin,
                 const float* __restrict__ b_lin,
                 float* __restrict__ out)
{
    // Arena (27136 B), region-overlaid (lifetimes):
    //   [0,8192):      X0 leaf half B-tile (16 rows); dead after leafB GEMM
    //                  -> h1 (L1 out rows 0..7 real at [0,4096); rows 8..15
    //                     stale X0 data read by L2's G=1 B-fetch, masked)
    //   [8192,16384):  h0 (leaf out, 16 rows, L1 B-tile); dead after L1 GEMM
    //                  -> h2 (L2 out rows 0..3 real at [8192,10240); rows
    //                     4..15 stale h0 data read by L3, masked)
    //   [16384,18432): h3 (L3 out, rows 0..1 real; 2KB reserved)
    //   [18432,27136): cAr [p=128][34] ushort in-place c-arena, whole kernel
    // + 88 ints of ids => ~27.5KB total -> 4 blocks/CU even at 8KiB LDS gran.
    __shared__ __align__(16) unsigned char arena[27136];
    __shared__ int ids0[32], ids1[16], ids2[8], tok[32];

    const int t    = threadIdx.x;
    const int lane = t & 63;
    const int w    = t >> 6;       // wave = p-slice, 8 waves
    const int lrow = lane & 15;
    const int lk   = lane >> 4;
    const int blk3 = blockIdx.x * 4;   // 4 level-3 roots per block

    // ---- id chase: local slot s's children are local slots 2s,2s+1 ----
    if (t < 4)  { int2 p = cpairs[196608 + blk3 + t]; ids2[2*t] = p.x; ids2[2*t+1] = p.y; }
    __syncthreads();
    if (t < 8)  { int2 p = cpairs[131072 + ids2[t]];  ids1[2*t] = p.x; ids1[2*t+1] = p.y; }
    __syncthreads();
    if (t < 16) { int2 p = cpairs[ids1[t]];           ids0[2*t] = p.x; ids0[2*t+1] = p.y; }
    __syncthreads();
    if (t < 32) { tok[t] = leaf_x[ids0[t]]; }
    __syncthreads();

    unsigned char*  X0  = arena;                             // -> h1
    unsigned char*  h0  = arena + 8192;                      // -> h2
    unsigned char*  h3  = arena + 16384;
    unsigned short* cAr = (unsigned short*)(arena + 18432);
    unsigned char*  h1  = arena;
    unsigned char*  h2  = arena + 8192;

    // ---- leaves: 32 nodes in two 16-row halves ----
    #pragma unroll 1
    for (int half = 0; half < 2; ++half) {
        {
            const int c = t & 31;       // 16B chunk
            const int r = t >> 5;       // [0,16)
            const int gi = tok[half * 16 + r];
            const float4* src = reinterpret_cast<const float4*>(
                emb + (size_t)gi * 256 + c * 8);
            float4 a = src[0], b = src[1];
            short8 v;
            v[0]=(short)f2bf(a.x); v[1]=(short)f2bf(a.y);
            v[2]=(short)f2bf(a.z); v[3]=(short)f2bf(a.w);
            v[4]=(short)f2bf(b.x); v[5]=(short)f2bf(b.y);
            v[6]=(short)f2bf(b.z); v[7]=(short)f2bf(b.w);
            *reinterpret_cast<short8*>(X0 + r * 512 + ((c ^ (r & 7)) << 4)) = v;
        }
        __syncthreads();
        level_step<3, 1, true>(Wl, X0, h0, cAr, b_iou, b_f,
                               w, lrow, lk, half * 16, 16);
        __syncthreads();
    }

    // ---- level 1: 16 nodes (B-tile = h0, all 16 rows real) ----
    logits_emit(h0, 32, ids0, 0, 0, W_lin, b_lin, out, t);
    level_step<5, 2, true>(Wc, h0, h1, cAr, b_iou, b_f,
                           w, lrow, lk, 0, 16);
    __syncthreads();

    // ---- level 2: 8 nodes (B rows 8..15 stale; masked) ----
    logits_emit(h1, 16, ids1, 0, 262144, W_lin, b_lin, out, t);
    level_step<5, 4, true>(Wc, h1, h2, cAr, b_iou, b_f,
                           w, lrow, lk, 0, 8);
    __syncthreads();

    // ---- level 3: 4 nodes (B rows 2..15 stale; masked) ----
    logits_emit(h2, 8, ids2, 0, 393216, W_lin, b_lin, out, t);
    level_step<5, 8, false>(Wc, h2, h3, cAr, b_iou, b_f,
                            w, lrow, lk, 0, 4);
    __syncthreads();

    logits_emit(h3, 4, nullptr, blk3, 458752, W_lin, b_lin, out, t);
}

// ---------------------------------------------------------------------------
extern "C" void kernel_launch(void* const* d_in, const int* in_sizes, int n_in,
                              void* d_out, int out_size, void* d_ws, size_t ws_size,
                              hipStream_t stream)
{
    const int*   leaf_x = (const int*)d_in[0];
    const int*   child  = (const int*)d_in[1];
    const float* emb    = (const float*)d_in[2];
    const float* W_iou  = (const float*)d_in[3];
    const float* U_iou  = (const float*)d_in[4];
    const float* b_iou  = (const float*)d_in[5];
    const float* U_f    = (const float*)d_in[6];
    const float* b_f    = (const float*)d_in[7];
    const float* W_lin  = (const float*)d_in[8];
    const float* b_lin  = (const float*)d_in[9];
    float* out = (float*)d_out;

    char* ws = (char*)d_ws;
    unsigned short* Wl = (unsigned short*)ws;                 // 192 KiB
    unsigned short* Wc = (unsigned short*)(ws + 196608);      // 320 KiB

    prep_kernel<<<384, 256, 0, stream>>>(W_iou, U_iou, U_f, Wl, Wc);

    tree_kernel<<<8192, THREADS, 0, stream>>>(
        leaf_x, (const int2*)child, emb, Wl, Wc,
        b_iou, b_f, W_lin, b_lin, out);
}

// Round 12
// 928.208 us; speedup vs baseline: 1.6386x; 1.6386x over previous
//
#include <hip/hip_runtime.h>
#include <hip/hip_bf16.h>
#include <stdint.h>

// TreeLSTM on MI355X (gfx950) — fully fused subtree kernel, v9.
// v9 = v7 body + logits pressure removal:
//  (1) chunk-wise logits dots (no hv[32] array -> no spill candidate),
//  (2) W_lin/b_iou/b_f preloaded to LDS (kills ~160 scalar global loads per
//      thread per level that went through the generic path),
//  (3) logits written DENSE+coalesced to d_ws with a gid map; a separate
//      massively-parallel scatter kernel applies b_lin and does the scattered
//      out[] stores -> no scattered-RMW vmcnt(0) drains inside tree_kernel.
// Keeps: in-place [p][66] c-arena, XOR-swizzled B-tiles, exp/rcp activations,
// (512,4) bounds, idempotent weight packing in d_ws.

#define THREADS 512

typedef __attribute__((ext_vector_type(8))) short short8;
typedef __attribute__((ext_vector_type(4))) float f32x4;

__device__ __forceinline__ unsigned short f2bf(float x) {
    unsigned u = __float_as_uint(x);
    u += 0x7fffu + ((u >> 16) & 1u);   // round-to-nearest-even
    return (unsigned short)(u >> 16);
}
__device__ __forceinline__ float bf2f(unsigned short b) {
    return __uint_as_float(((unsigned)b) << 16);
}
__device__ __forceinline__ float rcp_fast(float x) { return __builtin_amdgcn_rcpf(x); }
__device__ __forceinline__ float sigm(float x) { return rcp_fast(1.f + __expf(-x)); }
__device__ __forceinline__ float tanh_fast(float x) {
    float e = __expf(2.f * x);
    return (e - 1.f) * rcp_fast(e + 1.f);
}

// ---------------------------------------------------------------------------
// Pack W_iou (384x256) -> Wl ; [U_iou (384x256); U_f (256x256)] -> Wc (640x256)
__global__ __launch_bounds__(256)
void prep_kernel(const float* __restrict__ W_iou,
                 const float* __restrict__ U_iou,
                 const float* __restrict__ U_f,
                 unsigned short* __restrict__ Wl,
                 unsigned short* __restrict__ Wc)
{
    const int i = blockIdx.x * 256 + threadIdx.x;   // grid covers 98304
    if (i < 98304) {
        Wl[i] = f2bf(W_iou[i]);
        Wc[i] = f2bf(U_iou[i]);
    }
    if (i < 65536) {
        Wc[98304 + i] = f2bf(U_f[i]);
    }
}

// ---------------------------------------------------------------------------
// One level's GEMM + LSTM epilogue (unchanged from v7 except biases via LDS).
template<int NCOL, int G, int CW, bool WC>
__device__ __forceinline__ void level_step(
    const unsigned short* __restrict__ Wg,     // [NCOL*128][256] bf16, global
    const unsigned char* Blds,                 // B-tile base in LDS
    unsigned char* h_out,                      // LDS, B-tile format for next level
    unsigned short* cAr,                       // LDS c-arena, stride 66 per p
    const float* bias,                         // LDS: [0,384) b_iou, [384,640) b_f
    int w, int lrow, int lk, int slotBase, int mrows)
{
    const int q0 = w * 16;
    const unsigned char* wbase = reinterpret_cast<const unsigned char*>(Wg)
                               + (q0 + lrow) * 512 + lk * 16;

    f32x4 acc[NCOL][G];
    #pragma unroll
    for (int j = 0; j < NCOL; ++j)
        #pragma unroll
        for (int g = 0; g < G; ++g)
            acc[j][g] = (f32x4){0.f, 0.f, 0.f, 0.f};

    #pragma unroll
    for (int ks = 0; ks < 8; ++ks) {
        short8 aW[NCOL];
        #pragma unroll
        for (int j = 0; j < NCOL; ++j)
            aW[j] = *reinterpret_cast<const short8*>(
                wbase + j * 65536 + ks * 64);
        #pragma unroll
        for (int g = 0; g < G; ++g) {
            const int row = g * 16 + lrow;          // B-tile row
            const int chunk = (ks * 4 + lk) ^ (row & 7);
            short8 bN = *reinterpret_cast<const short8*>(
                Blds + row * 512 + (chunk << 4));
            #pragma unroll
            for (int j = 0; j < NCOL; ++j)
                acc[j][g] = __builtin_amdgcn_mfma_f32_16x16x32_bf16(
                    aW[j], bN, acc[j][g], 0, 0, 0);
        }
    }

    #pragma unroll
    for (int g = 0; g < G; ++g) {
        const int mlB = g * 16 + lrow;              // B-tile row index
        if (mlB < mrows) {
            const int ml = slotBase + mlB;          // output slot this level
            #pragma unroll
            for (int r = 0; r < 4; ++r) {
                const int p = q0 + lk * 4 + r;
                float iv = acc[0][g][r] + bias[p];
                float ov = acc[1][g][r] + bias[128 + p];
                float uv = acc[2][g][r] + bias[256 + p];
                float csum = 0.f;
                if (NCOL == 5) {
                    float f0 = acc[3][g][r] + bias[384 + p];
                    float f1 = acc[4][g][r] + bias[512 + p];
                    const int cb = p * 66 + CW * mlB;
                    csum = sigm(f0) * bf2f(cAr[cb])
                         + sigm(f1) * bf2f(cAr[cb + CW / 2]);
                }
                float cv = sigm(iv) * tanh_fast(uv) + csum;
                float hv = sigm(ov) * tanh_fast(cv);
                if (WC) cAr[p * 66 + CW * ml] = f2bf(cv);
                const int jr = ml >> 1;
                const int q = (ml & 1) * 16 + (p >> 3);
                *reinterpret_cast<unsigned short*>(
                    h_out + jr * 512 + ((q ^ (jr & 7)) << 4) + (p & 7) * 2)
                    = f2bf(hv);
            }
        }
    }
}

// logits dots for M local nodes from swizzled LDS h; 4 lanes per node.
// Chunk-wise accumulation (no hv[] array); W_lin read from LDS (broadcast).
// Dots (no bias) go to the LDS stash sL; written dense to d_ws at kernel end.
__device__ __forceinline__ void logits_stash(
    const unsigned char* h_lds, int M, int stBase,
    const float* Wl_lds, float* sL, int t)
{
    const int s = t >> 2, sub = t & 3;
    if (s >= M) return;
    const int j = s >> 1;
    float dots[5] = {0.f, 0.f, 0.f, 0.f, 0.f};
    #pragma unroll
    for (int qq = 0; qq < 4; ++qq) {
        const int q = (s & 1) * 16 + sub * 4 + qq;
        short8 v = *reinterpret_cast<const short8*>(
            h_lds + j * 512 + ((q ^ (j & 7)) << 4));
        #pragma unroll
        for (int e = 0; e < 8; ++e) {
            const float hv = bf2f((unsigned short)v[e]);
            const int k = sub * 32 + qq * 8 + e;
            #pragma unroll
            for (int cl = 0; cl < 5; ++cl)
                dots[cl] += hv * Wl_lds[cl * 128 + k];
        }
    }
    #pragma unroll
    for (int cl = 0; cl < 5; ++cl) {
        float d = dots[cl];
        d += __shfl_xor(d, 1);
        d += __shfl_xor(d, 2);
        if (sub == 0) sL[(stBase + s) * 5 + cl] = d;
    }
}

// Scatter dense per-block logits to out[] with b_lin; massively parallel,
// no barriers -> store latency fully overlapped across 1920 blocks.
__global__ __launch_bounds__(256)
void scatter_kernel(const float* __restrict__ dense,
                    const int* __restrict__ map,
                    const float* __restrict__ b_lin,
                    float* __restrict__ out)
{
    const int i = blockIdx.x * 256 + threadIdx.x;   // grid covers 491520
    const int g = map[i];
    const float* sp = dense + (size_t)i * 5;
    float* op = out + (size_t)g * 5;
    #pragma unroll
    for (int c = 0; c < 5; ++c) op[c] = sp[c] + b_lin[c];
}

// ---------------------------------------------------------------------------
__global__ __launch_bounds__(THREADS, 4)
void tree_kernel(const int*  __restrict__ leaf_x,
                 const int2* __restrict__ cpairs,   // l1:[0,131072) l2:+131072 l3:+196608
                 const float* __restrict__ emb,
                 const unsigned short* __restrict__ Wl,
                 const unsigned short* __restrict__ Wc,
                 const float* __restrict__ b_iou,
                 const float* __restrict__ b_f,
                 const float* __restrict__ W_lin,
                 float* __restrict__ denseL,        // ws: [4096][600] f32
                 int* __restrict__ mapL)            // ws: [4096][120] int
{
    // Arena (49664 B), region-overlaid — identical to v7.
    __shared__ __align__(16) unsigned char arena[49664];
    __shared__ int ids0[64], ids1[32], ids2[16], tok[64], sg[120];
    __shared__ float sL[600];
    __shared__ float bias[1280];   // [0,384) b_iou | [384,640) b_f | [640,1280) W_lin

    const int t    = threadIdx.x;
    const int lane = t & 63;
    const int w    = t >> 6;       // wave = p-slice, 8 waves
    const int lrow = lane & 15;
    const int lk   = lane >> 4;
    const int blk3 = blockIdx.x * 8;   // 8 level-3 roots per block

    // ---- preload biases + W_lin into LDS (coalesced) ----
    #pragma unroll
    for (int i = t; i < 1280; i += THREADS) {
        float v;
        if (i < 384)      v = b_iou[i];
        else if (i < 640) v = b_f[i - 384];
        else              v = W_lin[i - 640];
        bias[i] = v;
    }

    // ---- id chase: local slot s's children are local slots 2s,2s+1 ----
    if (t < 8)  { int2 p = cpairs[196608 + blk3 + t]; ids2[2*t] = p.x; ids2[2*t+1] = p.y; }
    __syncthreads();
    if (t < 16) { int2 p = cpairs[131072 + ids2[t]];  ids1[2*t] = p.x; ids1[2*t+1] = p.y; }
    __syncthreads();
    if (t < 32) { int2 p = cpairs[ids1[t]];           ids0[2*t] = p.x; ids0[2*t+1] = p.y; }
    __syncthreads();
    if      (t < 64)  { tok[t] = leaf_x[ids0[t]]; sg[t] = ids0[t]; }
    else if (t < 96)  { sg[t] = 262144 + ids1[t - 64]; }
    else if (t < 112) { sg[t] = 393216 + ids2[t - 96]; }
    else if (t < 120) { sg[t] = 458752 + blk3 + (t - 112); }
    __syncthreads();

    unsigned char*  X0  = arena;
    unsigned char*  h0  = arena + 16384;
    unsigned short* cAr = (unsigned short*)(arena + 32768);
    unsigned char*  h1  = arena;
    unsigned char*  h2  = arena + 16384;
    unsigned char*  h3  = arena + 8192;
    const float*    WlL = bias + 640;

    // ---- leaves: 64 nodes in two 32-row halves ----
    #pragma unroll 1
    for (int half = 0; half < 2; ++half) {
        {
            const int c  = t & 31;      // 16B chunk
            const int r0 = t >> 5;      // [0,16)
            #pragma unroll
            for (int rr = 0; rr < 2; ++rr) {
                const int r  = r0 + rr * 16;           // [0,32)
                const int gi = tok[half * 32 + r];
                const float4* src = reinterpret_cast<const float4*>(
                    emb + (size_t)gi * 256 + c * 8);
                float4 a = src[0], b = src[1];
                short8 v;
                v[0]=(short)f2bf(a.x); v[1]=(short)f2bf(a.y);
                v[2]=(short)f2bf(a.z); v[3]=(short)f2bf(a.w);
                v[4]=(short)f2bf(b.x); v[5]=(short)f2bf(b.y);
                v[6]=(short)f2bf(b.z); v[7]=(short)f2bf(b.w);
                *reinterpret_cast<short8*>(X0 + r * 512 + ((c ^ (r & 7)) << 4)) = v;
            }
        }
        __syncthreads();
        level_step<3, 2, 1, true>(Wl, X0, h0, cAr, bias,
                                  w, lrow, lk, half * 32, 32);
        __syncthreads();
    }

    // ---- level 1: 32 nodes ----
    logits_stash(h0, 64, 0, WlL, sL, t);
    level_step<5, 2, 2, true>(Wc, h0, h1, cAr, bias,
                              w, lrow, lk, 0, 32);
    __syncthreads();

    // ---- level 2: 16 nodes ----
    logits_stash(h1, 32, 64, WlL, sL, t);
    level_step<5, 1, 4, true>(Wc, h1, h2, cAr, bias,
                              w, lrow, lk, 0, 16);
    __syncthreads();

    // ---- level 3: 8 nodes (stale B rows 8..15 masked) ----
    logits_stash(h2, 16, 96, WlL, sL, t);
    level_step<5, 1, 8, false>(Wc, h2, h3, cAr, bias,
                               w, lrow, lk, 0, 8);
    __syncthreads();

    logits_stash(h3, 8, 112, WlL, sL, t);
    __syncthreads();

    // ---- dense, coalesced dump of this block's logits + gid map ----
    {
        float* dL = denseL + (size_t)blockIdx.x * 600;
        int*   mp = mapL   + (size_t)blockIdx.x * 120;
        if (t < 120) mp[t] = sg[t];
        for (int i = t; i < 600; i += THREADS) dL[i] = sL[i];
    }
}

// ---------------------------------------------------------------------------
extern "C" void kernel_launch(void* const* d_in, const int* in_sizes, int n_in,
                              void* d_out, int out_size, void* d_ws, size_t ws_size,
                              hipStream_t stream)
{
    const int*   leaf_x = (const int*)d_in[0];
    const int*   child  = (const int*)d_in[1];
    const float* emb    = (const float*)d_in[2];
    const float* W_iou  = (const float*)d_in[3];
    const float* U_iou  = (const float*)d_in[4];
    const float* b_iou  = (const float*)d_in[5];
    const float* U_f    = (const float*)d_in[6];
    const float* b_f    = (const float*)d_in[7];
    const float* W_lin  = (const float*)d_in[8];
    const float* b_lin  = (const float*)d_in[9];
    float* out = (float*)d_out;

    char* ws = (char*)d_ws;
    unsigned short* Wl = (unsigned short*)ws;                 // 192 KiB
    unsigned short* Wc = (unsigned short*)(ws + 196608);      // 320 KiB
    float* denseL = (float*)(ws + 524288);                    // 9.83 MB
    int*   mapL   = (int*)(ws + 524288 + 9830400);            // 1.97 MB

    prep_kernel<<<384, 256, 0, stream>>>(W_iou, U_iou, U_f, Wl, Wc);

    tree_kernel<<<4096, THREADS, 0, stream>>>(
        leaf_x, (const int2*)child, emb, Wl, Wc,
        b_iou, b_f, W_lin, denseL, mapL);

    scatter_kernel<<<1920, 256, 0, stream>>>(denseL, mapL, b_lin, out);
}